// Round 18
// baseline (98.229 us; speedup 1.0000x reference)
//
#include <hip/hip_runtime.h>

// DcorLoss: dcor(x, y) for x,y [8192,128] fp32 -> single scalar.
//
// <HaH,HbH> = sum(a_ij b_ij) - (2/n) sum_i ra_i rb_i + Sa Sb/n^2: fused pass
// over pair-tiles: bf16 gram -> distances -> scalar products + row/col sums.
// Upper triangle; off-diag doubled + transposed col-sums.
//
// R18: R17's 16-waves/CU design with the STAGING RACE FIXED. R17 issued
// stagec(buf, c+2) BEFORE the WAITV+gram that reads chunk c from the same
// buffer -> in-flight DMA could land mid-read (absmax 2e-2). Fix: R16's
// proven order -- each phase is WAITV(4); gram(buf); sched_barrier(0);
// stagec(buf, c+2). K=16 chunks + v_mfma_f32_16x16x16_bf16 (inline asm):
// ring-2 = 8KB + 1KB norms = 9.2KB/wave; 2 independent waves per 128-thr
// block (zero barriers) = 18.4KB -> 8 blocks/CU -> 16 waves/CU (vs R16's
// 9). Combine/butterfly/atomic epilogue identical to R15/R16.

typedef float f32x4 __attribute__((ext_vector_type(4)));
typedef __bf16 bf16x4 __attribute__((ext_vector_type(4)));
typedef __bf16 bf16x2 __attribute__((ext_vector_type(2)));

#define NR 8192
#define D 128
#define NB 128         /* row blocks of 64 */
#define NT2 8256       /* NB*(NB+1)/2 */
#define NBLK 4128      /* NT2 / 2 waves per block */

// ---------------- workspace layout (bytes) ----------------
#define OFF_YB  2097152u
#define OFF_NX  4194304u
#define OFF_NY  (OFF_NX + 32768u)
#define OFF_RX  (OFF_NY + 32768u)     /* 8192 f32 (zeroed by prep) */
#define OFF_RY  (OFF_RX + 32768u)     /* 8192 f32 (zeroed by prep) */
#define OFF_PP  (OFF_RY + 32768u)     /* 3*8256 f64 */
#define WS_NEED (OFF_PP + 198144u)

#define GLOAD_LDS16(g, l)                                                  \
    __builtin_amdgcn_global_load_lds(                                      \
        (const __attribute__((address_space(1))) unsigned*)(g),            \
        (__attribute__((address_space(3))) unsigned*)(l), 16, 0, 0)

#define WAITV(N)                                                           \
    do {                                                                   \
        asm volatile("s_waitcnt vmcnt(" #N ")" ::: "memory");              \
        __builtin_amdgcn_sched_barrier(0);                                 \
    } while (0)

#define SBARX() __builtin_amdgcn_sched_barrier(0)

__device__ __forceinline__ unsigned short bf16_rne(float f) {
    union { float f; unsigned u; } c; c.f = f;
    unsigned u = c.u;
    u += 0x7FFFu + ((u >> 16) & 1u);
    return (unsigned short)(u >> 16);
}

// One wave per row: fp32 -> bf16 (RNE), linear panels + fp32 row sq-norm.
// First 16384 threads also zero Rx/Ry.
__global__ __launch_bounds__(256) void prep_kernel(
    const float* __restrict__ x, const float* __restrict__ y,
    unsigned short* __restrict__ xb, unsigned short* __restrict__ yb,
    float* __restrict__ nx, float* __restrict__ ny,
    float* __restrict__ Rz /* Rx then Ry: 16384 f32 */)
{
    int gid = blockIdx.x * 256 + threadIdx.x;
    if (gid < 2 * NR) Rz[gid] = 0.f;
    int wave = gid >> 6;
    int lane = threadIdx.x & 63;
    const float* src; unsigned short* db; float* dn; int row;
    if (wave < NR) { src = x; db = xb; dn = nx; row = wave; }
    else           { src = y; db = yb; dn = ny; row = wave - NR; }

    const float2 v = *reinterpret_cast<const float2*>(src + (size_t)row * D + lane * 2);
    float s = v.x * v.x + v.y * v.y;
    unsigned packed = (unsigned)bf16_rne(v.x) | ((unsigned)bf16_rne(v.y) << 16);
    *reinterpret_cast<unsigned*>(db + (size_t)row * D + lane * 2) = packed;
#pragma unroll
    for (int m = 1; m < 64; m <<= 1) s += __shfl_xor(s, m);
    if (lane == 0) dn[row] = s;
}

// butterfly step S for a 16-value array reduced over the 16-lane lrow group
#define BSTEP(arr, S) {                                                    \
    const int b_ = (lrow >> (S)) & 1;                                      \
    _Pragma("unroll")                                                      \
    for (int i_ = 0; i_ < (8 >> (S)); ++i_) {                              \
        float k_ = b_ ? arr[2 * i_ + 1] : arr[2 * i_];                     \
        float s_ = b_ ? arr[2 * i_] : arr[2 * i_ + 1];                     \
        arr[i_] = k_ + __shfl_xor(s_, 1 << (S));                           \
    } }

// 128-thread blocks = 2 INDEPENDENT waves, each owning one 64x64 pair-tile
// (t = 2*block + wid). Per wave: private ring-2 of K=16 chunks (8KB) +
// 1KB norms; 16 phases; counted wave-local vmcnt; no barriers anywhere.
__global__ __launch_bounds__(128) void dcor_wave3(
    const unsigned short* __restrict__ xb, const unsigned short* __restrict__ yb,
    const float* __restrict__ nx, const float* __restrict__ ny,
    float* __restrict__ Rx, float* __restrict__ Ry,
    double* __restrict__ Pp /* [3][NT2] */)
{
    const int wid = threadIdx.x >> 6, lane = threadIdx.x & 63;
    // XCD-chunked block swizzle (NBLK % 8 == 0 -> bijective)
    const int bswz = (blockIdx.x & 7) * (NBLK / 8) + (blockIdx.x >> 3);
    const int t = bswz * 2 + wid;
    // triangular decode t -> (bi, bj), bi <= bj over NB=128
    double qd = 2.0 * NB + 1.0;
    int bi = (int)((qd - sqrt(qd * qd - 8.0 * (double)t)) * 0.5);
    while (bi > 0 && bi * NB - bi * (bi - 1) / 2 > t) --bi;
    while ((bi + 1) * NB - (bi + 1) * bi / 2 <= t) ++bi;
    const int bj = bi + (t - (bi * NB - bi * (bi - 1) / 2));
    const bool diag = (bi == bj);

    // [wave][ring2][A/B][64 rows][16 k] bf16; 16B granule g stored at
    // g ^ ((row>>2)&1)  (contiguity-preserving; reads <=2-way = free)
    __shared__ __align__(16) unsigned short Buf[2][2][2][64][16];
    __shared__ float nlds[2][4][64];
    float (*nl)[64] = nlds[wid];

    const int lrow = lane & 15, lkb = lane >> 4;

    // norms -> LDS (compiler's own waits drain these before use)
    nl[0][lane] = nx[bi * 64 + lane];
    nl[1][lane] = nx[bj * 64 + lane];
    nl[2][lane] = ny[bi * 64 + lane];
    nl[3][lane] = ny[bj * 64 + lane];
    SBARX();

    // stage chunk kc (K=16, both matrices) into ring buf b: 4 x 1KB gloads
    auto stagec = [&](int b, int kc) {
        const char* gb = (const char*)((kc < 8) ? xb : yb);
        const int kk = kc & 7;
#pragma unroll
        for (int mat = 0; mat < 2; ++mat) {
            int blk = mat ? bj : bi;
#pragma unroll
            for (int seg = 0; seg < 2; ++seg) {
                int row = seg * 32 + (lane >> 1);
                int g = (lane & 1) ^ ((row >> 2) & 1);
                const char* gsrc = gb + (size_t)(blk * 64 + row) * 256 + kk * 32 + g * 16;
                GLOAD_LDS16(gsrc, &Buf[wid][b][mat][seg * 32][0]);
            }
        }
    };

    // per-lane read offset within a 2KB chunk-matrix:
    // addr(row=m*16+lrow) = m*512 + lrow*32 + swz-granule*16 + half*8
    const int roff = lrow * 32 + (((lkb >> 1) ^ ((lrow >> 2) & 1)) << 4) + (lkb & 1) * 8;

    // one K=16 chunk: 8 ds_read_b64 + 16 x v_mfma_f32_16x16x16_bf16 (asm)
    auto gram = [&](int b, f32x4 (&acc)[4][4]) {
        const char* base = (const char*)&Buf[wid][b][0][0][0];
        bf16x4 av[4], bv[4];
#pragma unroll
        for (int m = 0; m < 4; ++m)
            av[m] = *reinterpret_cast<const bf16x4*>(base + m * 512 + roff);
#pragma unroll
        for (int nf = 0; nf < 4; ++nf)
            bv[nf] = *reinterpret_cast<const bf16x4*>(base + 2048 + nf * 512 + roff);
#pragma unroll
        for (int m = 0; m < 4; ++m)
#pragma unroll
            for (int nf = 0; nf < 4; ++nf)
                asm("v_mfma_f32_16x16x16_bf16 %0, %1, %2, %0"
                    : "+v"(acc[m][nf]) : "v"(av[m]), "v"(bv[nf]));
    };

    // C frag: row=(lane>>4)*4+r, col=lane&15 (same as 16x16x32 family).
    auto to_dist = [&](f32x4 (&acc)[4][4], int selR, int selC) {
        float nc[4];
#pragma unroll
        for (int nf = 0; nf < 4; ++nf) nc[nf] = nl[selC][nf * 16 + lrow];
#pragma unroll
        for (int m = 0; m < 4; ++m) {
            const f32x4 nr4 = *reinterpret_cast<const f32x4*>(
                &nl[selR][m * 16 + lkb * 4]);
#pragma unroll
            for (int nf = 0; nf < 4; ++nf)
#pragma unroll
                for (int r = 0; r < 4; ++r) {
                    float sq = nr4[r] + nc[nf] - 2.f * acc[m][nf][r];
                    acc[m][nf][r] = __builtin_amdgcn_sqrtf(fmaxf(sq, 0.f));
                }
        }
        if (diag) {
#pragma unroll
            for (int m = 0; m < 4; ++m)
#pragma unroll
                for (int nf = 0; nf < 4; ++nf)
#pragma unroll
                    for (int r = 0; r < 4; ++r) {
                        int row_l = m * 16 + lkb * 4 + r;
                        int col_l = nf * 16 + lrow;
                        if (row_l == col_l) acc[m][nf][r] = 0.f;
                    }
        }
    };

    const f32x4 fz = {0.f, 0.f, 0.f, 0.f};
    f32x4 accX[4][4];
#pragma unroll
    for (int m = 0; m < 4; ++m)
#pragma unroll
        for (int nf = 0; nf < 4; ++nf) accX[m][nf] = fz;

    // ---- 16-phase ring-2 pipeline: chunks c0..c15 = x k0-7, y k0-7 ----
    // Phase k: WAITV(4) retires chunk k; gram reads it; THEN stage chunk
    // k+2 into the just-read buffer (sched_barrier pins the order -- the
    // R17 race had the stage issued before the read).
    stagec(0, 0); stagec(1, 1);                          // vm 8
    WAITV(4); gram(0, accX); SBARX(); stagec(0, 2);      // P0  (c0)
    WAITV(4); gram(1, accX); SBARX(); stagec(1, 3);      // P1
    WAITV(4); gram(0, accX); SBARX(); stagec(0, 4);      // P2
    WAITV(4); gram(1, accX); SBARX(); stagec(1, 5);      // P3
    WAITV(4); gram(0, accX); SBARX(); stagec(0, 6);      // P4
    WAITV(4); gram(1, accX); SBARX(); stagec(1, 7);      // P5
    WAITV(4); gram(0, accX); SBARX(); stagec(0, 8);      // P6
    WAITV(4); gram(1, accX); SBARX(); stagec(1, 9);      // P7 (X done)
    asm volatile("s_nop 7\n\ts_nop 7");                  // MFMA->VALU gap
    to_dist(accX, 0, 1);
    unsigned dxb[32];                                    // X dists -> bf16
#pragma unroll
    for (int m = 0; m < 4; ++m)
#pragma unroll
        for (int nf = 0; nf < 4; ++nf)
#pragma unroll
            for (int rp = 0; rp < 2; ++rp) {
                bf16x2 pk;
                pk.x = (__bf16)accX[m][nf][2 * rp];
                pk.y = (__bf16)accX[m][nf][2 * rp + 1];
                dxb[(m * 4 + nf) * 2 + rp] = __builtin_bit_cast(unsigned, pk);
            }
    f32x4 accY[4][4];
#pragma unroll
    for (int m = 0; m < 4; ++m)
#pragma unroll
        for (int nf = 0; nf < 4; ++nf) accY[m][nf] = fz;
    SBARX();
    WAITV(4); gram(0, accY); SBARX(); stagec(0, 10);     // P8  (c8)
    WAITV(4); gram(1, accY); SBARX(); stagec(1, 11);     // P9
    WAITV(4); gram(0, accY); SBARX(); stagec(0, 12);     // P10
    WAITV(4); gram(1, accY); SBARX(); stagec(1, 13);     // P11
    WAITV(4); gram(0, accY); SBARX(); stagec(0, 14);     // P12
    WAITV(4); gram(1, accY); SBARX(); stagec(1, 15);     // P13
    WAITV(4); gram(0, accY);                             // P14 (c14)
    WAITV(0); gram(1, accY);                             // P15 (c15)
    asm volatile("s_nop 7\n\ts_nop 7");
    to_dist(accY, 2, 3);

    // ---- combine ----
    float pxy = 0.f, pxx = 0.f, pyy = 0.f;
    float ax[16], ay[16], csx[4], csy[4];
#pragma unroll
    for (int j = 0; j < 16; ++j) { ax[j] = 0.f; ay[j] = 0.f; }
#pragma unroll
    for (int j = 0; j < 4; ++j) { csx[j] = 0.f; csy[j] = 0.f; }

#pragma unroll
    for (int m = 0; m < 4; ++m)
#pragma unroll
        for (int nf = 0; nf < 4; ++nf)
#pragma unroll
            for (int rp = 0; rp < 2; ++rp) {
                unsigned u = dxb[(m * 4 + nf) * 2 + rp];
                float dx0 = __builtin_bit_cast(float, u << 16);
                float dx1 = __builtin_bit_cast(float, u & 0xFFFF0000u);
                float dy0 = accY[m][nf][2 * rp], dy1 = accY[m][nf][2 * rp + 1];
                pxy += dx0 * dy0 + dx1 * dy1;
                pxx += dx0 * dx0 + dx1 * dx1;
                pyy += dy0 * dy0 + dy1 * dy1;
                ax[m * 4 + 2 * rp] += dx0; ax[m * 4 + 2 * rp + 1] += dx1;
                ay[m * 4 + 2 * rp] += dy0; ay[m * 4 + 2 * rp + 1] += dy1;
                csx[nf] += dx0 + dx1;      csy[nf] += dy0 + dy1;
            }

    // butterfly: lane j=lrow owns row (j>>2)*16 + lkb*4 + (j&3) (bijective)
    BSTEP(ax, 0) BSTEP(ay, 0)
    BSTEP(ax, 1) BSTEP(ay, 1)
    BSTEP(ax, 2) BSTEP(ay, 2)
    BSTEP(ax, 3) BSTEP(ay, 3)
    {
        int row_l = ((lrow >> 2) << 4) + (lkb << 2) + (lrow & 3);
        atomicAdd(&Rx[bi * 64 + row_l], ax[0]);
        atomicAdd(&Ry[bi * 64 + row_l], ay[0]);
    }
    // col sums across lkb groups -> transposed rows (off-diag only)
#pragma unroll
    for (int nf = 0; nf < 4; ++nf) {
        float vx = csx[nf], vy = csy[nf];
        vx += __shfl_xor(vx, 16); vx += __shfl_xor(vx, 32);
        vy += __shfl_xor(vy, 16); vy += __shfl_xor(vy, 32);
        if (lkb == 0 && !diag) {
            atomicAdd(&Rx[bj * 64 + nf * 16 + lrow], vx);
            atomicAdd(&Ry[bj * 64 + nf * 16 + lrow], vy);
        }
    }
    // scalar products: full-wave reduce, lane 0 writes unique Pp slot
#pragma unroll
    for (int m = 1; m < 64; m <<= 1) {
        pxy += __shfl_xor(pxy, m);
        pxx += __shfl_xor(pxx, m);
        pyy += __shfl_xor(pyy, m);
    }
    if (lane == 0) {
        double sc = diag ? 1.0 : 2.0;
        Pp[t] = (double)pxy * sc;
        Pp[NT2 + t] = (double)pxx * sc;
        Pp[2 * NT2 + t] = (double)pyy * sc;
    }
}

__global__ __launch_bounds__(256) void dcor_final4(
    const float* __restrict__ Rx, const float* __restrict__ Ry,
    const double* __restrict__ Pp, unsigned* __restrict__ out)
{
    double sx = 0, sy = 0, sxy = 0, sxx = 0, syy = 0, pxy = 0, pxx = 0, pyy = 0;
    for (int i = threadIdx.x; i < NR; i += 256) {
        double rx = (double)Rx[i], ry = (double)Ry[i];
        sx += rx; sy += ry; sxy += rx * ry; sxx += rx * rx; syy += ry * ry;
    }
    for (int b = threadIdx.x; b < NT2; b += 256) {
        pxy += Pp[b]; pxx += Pp[NT2 + b]; pyy += Pp[2 * NT2 + b];
    }
    __shared__ double red[8][4];
    int lane = threadIdx.x & 63, w = threadIdx.x >> 6;
#pragma unroll
    for (int m = 1; m < 64; m <<= 1) {
        sx += __shfl_xor(sx, m);  sy += __shfl_xor(sy, m);
        sxy += __shfl_xor(sxy, m); sxx += __shfl_xor(sxx, m); syy += __shfl_xor(syy, m);
        pxy += __shfl_xor(pxy, m); pxx += __shfl_xor(pxx, m); pyy += __shfl_xor(pyy, m);
    }
    if (lane == 0) {
        red[0][w] = sx;  red[1][w] = sy;  red[2][w] = sxy; red[3][w] = sxx;
        red[4][w] = syy; red[5][w] = pxy; red[6][w] = pxx; red[7][w] = pyy;
    }
    __syncthreads();
    if (threadIdx.x == 0) {
        sx  = red[0][0] + red[0][1] + red[0][2] + red[0][3];
        sy  = red[1][0] + red[1][1] + red[1][2] + red[1][3];
        sxy = red[2][0] + red[2][1] + red[2][2] + red[2][3];
        sxx = red[3][0] + red[3][1] + red[3][2] + red[3][3];
        syy = red[4][0] + red[4][1] + red[4][2] + red[4][3];
        pxy = red[5][0] + red[5][1] + red[5][2] + red[5][3];
        pxx = red[6][0] + red[6][1] + red[6][2] + red[6][3];
        pyy = red[7][0] + red[7][1] + red[7][2] + red[7][3];
        const double inv = 1.0 / (double)NR;
        double vxy = pxy - 2.0 * inv * sxy + sx * sy * inv * inv;
        double vxx = pxx - 2.0 * inv * sxx + sx * sx * inv * inv;
        double vyy = pyy - 2.0 * inv * syy + sy * sy * inv * inv;
        vxy = fmax(vxy, 0.0);
        vxx = fmax(vxx, 1e-30); vyy = fmax(vyy, 1e-30);
        double dcor = -sqrt(vxy) / sqrt(sqrt(vxx) * sqrt(vyy));
        unsigned short b = bf16_rne((float)dcor);
        out[0] = ((unsigned)b << 16) | (unsigned)b;   // f32-and-bf16 valid
    }
}

extern "C" void kernel_launch(void* const* d_in, const int* in_sizes, int n_in,
                              void* d_out, int out_size, void* d_ws, size_t ws_size,
                              hipStream_t stream)
{
    const float* x = (const float*)d_in[0];
    const float* y = (const float*)d_in[1];
    char* ws = (char*)d_ws;
    unsigned short* xb = (unsigned short*)(ws);
    unsigned short* yb = (unsigned short*)(ws + OFF_YB);
    float* nx = (float*)(ws + OFF_NX);
    float* ny = (float*)(ws + OFF_NY);
    float* Rx = (float*)(ws + OFF_RX);
    float* Ry = (float*)(ws + OFF_RY);
    double* Pp = (double*)(ws + OFF_PP);

    prep_kernel<<<4096, 256, 0, stream>>>(x, y, xb, yb, nx, ny, Rx);
    dcor_wave3<<<NBLK, 128, 0, stream>>>(xb, yb, nx, ny, Rx, Ry, Pp);
    dcor_final4<<<1, 256, 0, stream>>>(Rx, Ry, Pp, (unsigned*)d_out);
}

// Round 19
// 97.081 us; speedup vs baseline: 1.0118x; 1.0118x over previous
//
#include <hip/hip_runtime.h>

// DcorLoss: dcor(x, y) for x,y [8192,128] fp32 -> single scalar.
//
// <HaH,HbH> = sum(a_ij b_ij) - (2/n) sum_i ra_i rb_i + Sa Sb/n^2: fused pass
// over pair-tiles: bf16 gram -> distances -> scalar products + row/col sums.
// Upper triangle; off-diag doubled + transposed col-sums.
//
// R19: DEFEAT THE DISPATCH-RATE CAP. R15/R16/R18 all measured ~3 resident
// blocks/CU regardless of static LDS/VGPR limits -> command-processor
// dispatch rate (~120 blocks/us) x block lifetime (~6.4us) bounds
// residency; tiny 1-2 wave blocks can never fill the machine. Fix: 4
// INDEPENDENT zero-sync waves per 256-thread block (wave w owns tile
// 4*block+w; no barriers; each wave runs R16's proven private ring-2
// K=32 b128 counted-vmcnt pipeline unchanged). LDS 4x17.4KB = 69.6KB ->
// 2 blocks/CU static = 8 waves/CU, and only 2064 blocks are needed ->
// CP rate no longer binds. Epilogue identical to R15/R16/R18.

typedef float f32x4 __attribute__((ext_vector_type(4)));
typedef __bf16 bf16x8 __attribute__((ext_vector_type(8)));
typedef __bf16 bf16x2 __attribute__((ext_vector_type(2)));

#define NR 8192
#define D 128
#define NB 128         /* row blocks of 64 */
#define NT2 8256       /* NB*(NB+1)/2 */
#define NBLK 2064      /* NT2 / 4 waves per block */

// ---------------- workspace layout (bytes) ----------------
#define OFF_YB  2097152u
#define OFF_NX  4194304u
#define OFF_NY  (OFF_NX + 32768u)
#define OFF_RX  (OFF_NY + 32768u)     /* 8192 f32 (zeroed by prep) */
#define OFF_RY  (OFF_RX + 32768u)     /* 8192 f32 (zeroed by prep) */
#define OFF_PP  (OFF_RY + 32768u)     /* 3*8256 f64 */
#define WS_NEED (OFF_PP + 198144u)

#define GLOAD_LDS16(g, l)                                                  \
    __builtin_amdgcn_global_load_lds(                                      \
        (const __attribute__((address_space(1))) unsigned*)(g),            \
        (__attribute__((address_space(3))) unsigned*)(l), 16, 0, 0)

#define WAITV(N)                                                           \
    do {                                                                   \
        asm volatile("s_waitcnt vmcnt(" #N ")" ::: "memory");              \
        __builtin_amdgcn_sched_barrier(0);                                 \
    } while (0)

__device__ __forceinline__ unsigned short bf16_rne(float f) {
    union { float f; unsigned u; } c; c.f = f;
    unsigned u = c.u;
    u += 0x7FFFu + ((u >> 16) & 1u);
    return (unsigned short)(u >> 16);
}

// One wave per row: fp32 -> bf16 (RNE), linear panels + fp32 row sq-norm.
// First 16384 threads also zero Rx/Ry.
__global__ __launch_bounds__(256) void prep_kernel(
    const float* __restrict__ x, const float* __restrict__ y,
    unsigned short* __restrict__ xb, unsigned short* __restrict__ yb,
    float* __restrict__ nx, float* __restrict__ ny,
    float* __restrict__ Rz /* Rx then Ry: 16384 f32 */)
{
    int gid = blockIdx.x * 256 + threadIdx.x;
    if (gid < 2 * NR) Rz[gid] = 0.f;
    int wave = gid >> 6;
    int lane = threadIdx.x & 63;
    const float* src; unsigned short* db; float* dn; int row;
    if (wave < NR) { src = x; db = xb; dn = nx; row = wave; }
    else           { src = y; db = yb; dn = ny; row = wave - NR; }

    const float2 v = *reinterpret_cast<const float2*>(src + (size_t)row * D + lane * 2);
    float s = v.x * v.x + v.y * v.y;
    unsigned packed = (unsigned)bf16_rne(v.x) | ((unsigned)bf16_rne(v.y) << 16);
    *reinterpret_cast<unsigned*>(db + (size_t)row * D + lane * 2) = packed;
#pragma unroll
    for (int m = 1; m < 64; m <<= 1) s += __shfl_xor(s, m);
    if (lane == 0) dn[row] = s;
}

// butterfly step S for a 16-value array reduced over the 16-lane lrow group
#define BSTEP(arr, S) {                                                    \
    const int b_ = (lrow >> (S)) & 1;                                      \
    _Pragma("unroll")                                                      \
    for (int i_ = 0; i_ < (8 >> (S)); ++i_) {                              \
        float k_ = b_ ? arr[2 * i_ + 1] : arr[2 * i_];                     \
        float s_ = b_ ? arr[2 * i_] : arr[2 * i_ + 1];                     \
        arr[i_] = k_ + __shfl_xor(s_, 1 << (S));                           \
    } }

// 256-thread blocks = 4 INDEPENDENT waves, each owning one 64x64 pair-tile
// (t = 4*block + wid). Per wave: private ring-2 of K=32 chunks (16KB) +
// 1KB norms; 8 phases; counted wave-local vmcnt; NO barriers anywhere.
__global__ __launch_bounds__(256) void dcor_wave4(
    const unsigned short* __restrict__ xb, const unsigned short* __restrict__ yb,
    const float* __restrict__ nx, const float* __restrict__ ny,
    float* __restrict__ Rx, float* __restrict__ Ry,
    double* __restrict__ Pp /* [3][NT2] */)
{
    const int wid = threadIdx.x >> 6, lane = threadIdx.x & 63;
    // XCD-chunked block swizzle (NBLK % 8 == 0 -> bijective)
    const int bswz = (blockIdx.x & 7) * (NBLK / 8) + (blockIdx.x >> 3);
    const int t = bswz * 4 + wid;
    // triangular decode t -> (bi, bj), bi <= bj over NB=128
    double qd = 2.0 * NB + 1.0;
    int bi = (int)((qd - sqrt(qd * qd - 8.0 * (double)t)) * 0.5);
    while (bi > 0 && bi * NB - bi * (bi - 1) / 2 > t) --bi;
    while ((bi + 1) * NB - (bi + 1) * bi / 2 <= t) ++bi;
    const int bj = bi + (t - (bi * NB - bi * (bi - 1) / 2));
    const bool diag = (bi == bj);

    // per-wave: [ring2][A/B][64 rows][32 bf16]; 16B granule q stored at
    // q ^ ((row>>1)&3)  (gload-contiguous; reads <=2-way = free)
    __shared__ __align__(16) unsigned short Buf[4][2][2][64][32];
    __shared__ float nlds[4][4][64];
    float (*nl)[64] = nlds[wid];

    const int lrow = lane & 15, lkb = lane >> 4;

    // norms -> LDS (wave-local; compiler's own waits order this)
    nl[0][lane] = nx[bi * 64 + lane];
    nl[1][lane] = nx[bj * 64 + lane];
    nl[2][lane] = ny[bi * 64 + lane];
    nl[3][lane] = ny[bj * 64 + lane];
    __builtin_amdgcn_sched_barrier(0);

    // stage chunk kc (K=32, both matrices) into ring buf b: 8 x 1KB gloads
    auto stagec = [&](int b, const unsigned short* srcb, int kc) {
        const char* gb = (const char*)srcb;
#pragma unroll
        for (int w = 0; w < 2; ++w) {
            int blk = w ? bj : bi;
#pragma unroll
            for (int seg = 0; seg < 4; ++seg) {
                int r = seg * 16 + (lane >> 2);
                int c = (lane & 3) ^ ((r >> 1) & 3);     // logical sub-chunk
                const char* g = gb + (size_t)(blk * 64 + r) * 256 + kc * 64 + c * 16;
                GLOAD_LDS16(g, &Buf[wid][b][w][seg * 16][0]);
            }
        }
    };

    // swizzled read offset: uniform across m since (m*16)>>1 ≡ 0 (mod 4)
    const int sA = (lkb ^ ((lrow >> 1) & 3)) << 4;

    auto gram = [&](int b, f32x4 (&acc)[4][4]) {
        const char* A = (const char*)&Buf[wid][b][0][0][0];
        const char* B = (const char*)&Buf[wid][b][1][0][0];
        bf16x8 av[4], bv[4];
#pragma unroll
        for (int m = 0; m < 4; ++m)
            av[m] = *reinterpret_cast<const bf16x8*>(A + (m * 16 + lrow) * 64 + sA);
#pragma unroll
        for (int nf = 0; nf < 4; ++nf)
            bv[nf] = *reinterpret_cast<const bf16x8*>(B + (nf * 16 + lrow) * 64 + sA);
#pragma unroll
        for (int m = 0; m < 4; ++m)
#pragma unroll
            for (int nf = 0; nf < 4; ++nf)
                acc[m][nf] = __builtin_amdgcn_mfma_f32_16x16x32_bf16(
                    av[m], bv[nf], acc[m][nf], 0, 0, 0);
    };

    // C frag: row=(lane>>4)*4+r, col=lane&15. Raw v_sqrt; LDS norms.
    auto to_dist = [&](f32x4 (&acc)[4][4], int selR, int selC) {
        float nc[4];
#pragma unroll
        for (int nf = 0; nf < 4; ++nf) nc[nf] = nl[selC][nf * 16 + lrow];
#pragma unroll
        for (int m = 0; m < 4; ++m) {
            const f32x4 nr4 = *reinterpret_cast<const f32x4*>(
                &nl[selR][m * 16 + lkb * 4]);
#pragma unroll
            for (int nf = 0; nf < 4; ++nf)
#pragma unroll
                for (int r = 0; r < 4; ++r) {
                    float sq = nr4[r] + nc[nf] - 2.f * acc[m][nf][r];
                    acc[m][nf][r] = __builtin_amdgcn_sqrtf(fmaxf(sq, 0.f));
                }
        }
        if (diag) {
#pragma unroll
            for (int m = 0; m < 4; ++m)
#pragma unroll
                for (int nf = 0; nf < 4; ++nf)
#pragma unroll
                    for (int r = 0; r < 4; ++r) {
                        int row_l = m * 16 + lkb * 4 + r;
                        int col_l = nf * 16 + lrow;
                        if (row_l == col_l) acc[m][nf][r] = 0.f;
                    }
        }
    };

    const f32x4 fz = {0.f, 0.f, 0.f, 0.f};
    f32x4 accX[4][4];
#pragma unroll
    for (int m = 0; m < 4; ++m)
#pragma unroll
        for (int nf = 0; nf < 4; ++nf) accX[m][nf] = fz;

    // ---- ring-2 wave-private pipeline: c0..c7 = x0-3,y0-3; buf = c&1 ----
    // (R16's proven order: restage of buf b targets the buffer consumed
    // in the PREVIOUS phase; stage precedes wait+gram of the other buf.)
    stagec(0, xb, 0);                                    // vm 8
    stagec(1, xb, 1); WAITV(8); gram(0, accX);           // P0 (c0)
    stagec(0, xb, 2); WAITV(8); gram(1, accX);           // P1 (c1)
    stagec(1, xb, 3); WAITV(8); gram(0, accX);           // P2 (c2)
    stagec(0, yb, 0); WAITV(8); gram(1, accX);           // P3 (c3) accX done
    // X distances -> packed bf16 while y0 flies
    to_dist(accX, 0, 1);
    unsigned dxb[32];
#pragma unroll
    for (int m = 0; m < 4; ++m)
#pragma unroll
        for (int nf = 0; nf < 4; ++nf)
#pragma unroll
            for (int rp = 0; rp < 2; ++rp) {
                bf16x2 pk;
                pk.x = (__bf16)accX[m][nf][2 * rp];
                pk.y = (__bf16)accX[m][nf][2 * rp + 1];
                dxb[(m * 4 + nf) * 2 + rp] = __builtin_bit_cast(unsigned, pk);
            }
    f32x4 accY[4][4];
#pragma unroll
    for (int m = 0; m < 4; ++m)
#pragma unroll
        for (int nf = 0; nf < 4; ++nf) accY[m][nf] = fz;
    stagec(1, yb, 1); WAITV(8); gram(0, accY);           // P4 (c4=y0)
    stagec(0, yb, 2); WAITV(8); gram(1, accY);           // P5 (c5=y1)
    stagec(1, yb, 3); WAITV(8); gram(0, accY);           // P6 (c6=y2)
    WAITV(0); gram(1, accY);                             // P7 (c7=y3)
    to_dist(accY, 2, 3);

    // ---- combine ----
    float pxy = 0.f, pxx = 0.f, pyy = 0.f;
    float ax[16], ay[16], csx[4], csy[4];
#pragma unroll
    for (int j = 0; j < 16; ++j) { ax[j] = 0.f; ay[j] = 0.f; }
#pragma unroll
    for (int j = 0; j < 4; ++j) { csx[j] = 0.f; csy[j] = 0.f; }

#pragma unroll
    for (int m = 0; m < 4; ++m)
#pragma unroll
        for (int nf = 0; nf < 4; ++nf)
#pragma unroll
            for (int rp = 0; rp < 2; ++rp) {
                unsigned u = dxb[(m * 4 + nf) * 2 + rp];
                float dx0 = __builtin_bit_cast(float, u << 16);
                float dx1 = __builtin_bit_cast(float, u & 0xFFFF0000u);
                float dy0 = accY[m][nf][2 * rp], dy1 = accY[m][nf][2 * rp + 1];
                pxy += dx0 * dy0 + dx1 * dy1;
                pxx += dx0 * dx0 + dx1 * dx1;
                pyy += dy0 * dy0 + dy1 * dy1;
                ax[m * 4 + 2 * rp] += dx0; ax[m * 4 + 2 * rp + 1] += dx1;
                ay[m * 4 + 2 * rp] += dy0; ay[m * 4 + 2 * rp + 1] += dy1;
                csx[nf] += dx0 + dx1;      csy[nf] += dy0 + dy1;
            }

    // butterfly: lane j=lrow owns row (j>>2)*16 + lkb*4 + (j&3) (bijective)
    BSTEP(ax, 0) BSTEP(ay, 0)
    BSTEP(ax, 1) BSTEP(ay, 1)
    BSTEP(ax, 2) BSTEP(ay, 2)
    BSTEP(ax, 3) BSTEP(ay, 3)
    {
        int row_l = ((lrow >> 2) << 4) + (lkb << 2) + (lrow & 3);
        atomicAdd(&Rx[bi * 64 + row_l], ax[0]);
        atomicAdd(&Ry[bi * 64 + row_l], ay[0]);
    }
    // col sums across lkb groups -> transposed rows (off-diag only)
#pragma unroll
    for (int nf = 0; nf < 4; ++nf) {
        float vx = csx[nf], vy = csy[nf];
        vx += __shfl_xor(vx, 16); vx += __shfl_xor(vx, 32);
        vy += __shfl_xor(vy, 16); vy += __shfl_xor(vy, 32);
        if (lkb == 0 && !diag) {
            atomicAdd(&Rx[bj * 64 + nf * 16 + lrow], vx);
            atomicAdd(&Ry[bj * 64 + nf * 16 + lrow], vy);
        }
    }
    // scalar products: full-wave reduce, lane 0 writes unique Pp slot
#pragma unroll
    for (int m = 1; m < 64; m <<= 1) {
        pxy += __shfl_xor(pxy, m);
        pxx += __shfl_xor(pxx, m);
        pyy += __shfl_xor(pyy, m);
    }
    if (lane == 0) {
        double sc = diag ? 1.0 : 2.0;
        Pp[t] = (double)pxy * sc;
        Pp[NT2 + t] = (double)pxx * sc;
        Pp[2 * NT2 + t] = (double)pyy * sc;
    }
}

__global__ __launch_bounds__(256) void dcor_final4(
    const float* __restrict__ Rx, const float* __restrict__ Ry,
    const double* __restrict__ Pp, unsigned* __restrict__ out)
{
    double sx = 0, sy = 0, sxy = 0, sxx = 0, syy = 0, pxy = 0, pxx = 0, pyy = 0;
    for (int i = threadIdx.x; i < NR; i += 256) {
        double rx = (double)Rx[i], ry = (double)Ry[i];
        sx += rx; sy += ry; sxy += rx * ry; sxx += rx * rx; syy += ry * ry;
    }
    for (int b = threadIdx.x; b < NT2; b += 256) {
        pxy += Pp[b]; pxx += Pp[NT2 + b]; pyy += Pp[2 * NT2 + b];
    }
    __shared__ double red[8][4];
    int lane = threadIdx.x & 63, w = threadIdx.x >> 6;
#pragma unroll
    for (int m = 1; m < 64; m <<= 1) {
        sx += __shfl_xor(sx, m);  sy += __shfl_xor(sy, m);
        sxy += __shfl_xor(sxy, m); sxx += __shfl_xor(sxx, m); syy += __shfl_xor(syy, m);
        pxy += __shfl_xor(pxy, m); pxx += __shfl_xor(pxx, m); pyy += __shfl_xor(pyy, m);
    }
    if (lane == 0) {
        red[0][w] = sx;  red[1][w] = sy;  red[2][w] = sxy; red[3][w] = sxx;
        red[4][w] = syy; red[5][w] = pxy; red[6][w] = pxx; red[7][w] = pyy;
    }
    __syncthreads();
    if (threadIdx.x == 0) {
        sx  = red[0][0] + red[0][1] + red[0][2] + red[0][3];
        sy  = red[1][0] + red[1][1] + red[1][2] + red[1][3];
        sxy = red[2][0] + red[2][1] + red[2][2] + red[2][3];
        sxx = red[3][0] + red[3][1] + red[3][2] + red[3][3];
        syy = red[4][0] + red[4][1] + red[4][2] + red[4][3];
        pxy = red[5][0] + red[5][1] + red[5][2] + red[5][3];
        pxx = red[6][0] + red[6][1] + red[6][2] + red[6][3];
        pyy = red[7][0] + red[7][1] + red[7][2] + red[7][3];
        const double inv = 1.0 / (double)NR;
        double vxy = pxy - 2.0 * inv * sxy + sx * sy * inv * inv;
        double vxx = pxx - 2.0 * inv * sxx + sx * sx * inv * inv;
        double vyy = pyy - 2.0 * inv * syy + sy * sy * inv * inv;
        vxy = fmax(vxy, 0.0);
        vxx = fmax(vxx, 1e-30); vyy = fmax(vyy, 1e-30);
        double dcor = -sqrt(vxy) / sqrt(sqrt(vxx) * sqrt(vyy));
        unsigned short b = bf16_rne((float)dcor);
        out[0] = ((unsigned)b << 16) | (unsigned)b;   // f32-and-bf16 valid
    }
}

extern "C" void kernel_launch(void* const* d_in, const int* in_sizes, int n_in,
                              void* d_out, int out_size, void* d_ws, size_t ws_size,
                              hipStream_t stream)
{
    const float* x = (const float*)d_in[0];
    const float* y = (const float*)d_in[1];
    char* ws = (char*)d_ws;
    unsigned short* xb = (unsigned short*)(ws);
    unsigned short* yb = (unsigned short*)(ws + OFF_YB);
    float* nx = (float*)(ws + OFF_NX);
    float* ny = (float*)(ws + OFF_NY);
    float* Rx = (float*)(ws + OFF_RX);
    float* Ry = (float*)(ws + OFF_RY);
    double* Pp = (double*)(ws + OFF_PP);

    prep_kernel<<<4096, 256, 0, stream>>>(x, y, xb, yb, nx, ny, Rx);
    dcor_wave4<<<NBLK, 256, 0, stream>>>(xb, yb, nx, ny, Rx, Ry, Pp);
    dcor_final4<<<1, 256, 0, stream>>>(Rx, Ry, Pp, (unsigned*)d_out);
}